// Round 3
// baseline (4004.596 us; speedup 1.0000x reference)
//
#include <hip/hip_runtime.h>
#include <hip/hip_bf16.h>

// Problem constants
#define BATCH 128
#define TSTEPS 64
#define EMB 256
#define HID 512
#define GATES 2048   // 4*HID
#define NFEAT 2048

typedef __bf16 bf16_t;
typedef __attribute__((ext_vector_type(8))) __bf16 bf16x8;
typedef __attribute__((ext_vector_type(4))) float f32x4;

#define MFMA16 __builtin_amdgcn_mfma_f32_16x16x32_bf16

// A/B fragment from row-major global: lane l -> row = row0 + (l&15), k = k0 + (l>>4)*8.
// Consistent bijective K-permutation for A and B cancels in GEMM; C/D mapping is verified.
__device__ __forceinline__ bf16x8 frag16(const bf16_t* __restrict__ base, int row0, int stride,
                                         int k0, int lane) {
    return *(const bf16x8*)(base + (size_t)(row0 + (lane & 15)) * stride + k0 + ((lane >> 4) << 3));
}

__device__ __forceinline__ float sigm(float x) { return 1.f / (1.f + __expf(-x)); }
__device__ __forceinline__ float tanh_f(float x) { return 1.f - 2.f / (__expf(2.f * x) + 1.f); }

// ---------------- prep: weights->bf16, gather emb (t-major), bias sum ----------------
__global__ __launch_bounds__(256) void k_prep(
    const float* __restrict__ Wih, const float* __restrict__ Whh, const float* __restrict__ Wout,
    const float* __restrict__ bih, const float* __restrict__ bhh,
    const int* __restrict__ m, const float* __restrict__ emb_tab,
    bf16_t* __restrict__ wih_b, bf16_t* __restrict__ whh_b, bf16_t* __restrict__ wout_b,
    float* __restrict__ biassum, bf16_t* __restrict__ emb_b) {
    const int N1 = GATES * EMB;          // Wih
    const int N2 = GATES * HID;          // Whh
    const int N3 = NFEAT * HID;          // Wout
    const int N4 = GATES;                // bias sum
    const int N5 = BATCH * TSTEPS * EMB; // gather (t-major rows)
    const long total = (long)N1 + N2 + N3 + N4 + N5;
    for (long i = (long)blockIdx.x * blockDim.x + threadIdx.x; i < total;
         i += (long)gridDim.x * blockDim.x) {
        long x = i;
        if (x < N1) { wih_b[x] = (bf16_t)Wih[x]; continue; } x -= N1;
        if (x < N2) { whh_b[x] = (bf16_t)Whh[x]; continue; } x -= N2;
        if (x < N3) { wout_b[x] = (bf16_t)Wout[x]; continue; } x -= N3;
        if (x < N4) { biassum[x] = bih[x] + bhh[x]; continue; } x -= N4;
        {
            int e = (int)(x & (EMB - 1));
            int rt = (int)(x >> 8);            // rt = t*128 + b  (t-major)
            int t = rt >> 7, b = rt & 127;
            int tok = m[b * TSTEPS + t];
            emb_b[x] = (bf16_t)emb_tab[(size_t)tok * EMB + e];
        }
    }
}

// ---------------- x_proj GEMM: emb[8192,256] x Wih^T -> xproj bf16 [t*128+b][2048] (+bias) ----
__global__ __launch_bounds__(256) void k_xproj(
    const bf16_t* __restrict__ A,     // emb_b [8192][256], row = t*128+b
    const bf16_t* __restrict__ Wih,   // [2048][256]
    const float* __restrict__ biassum,
    bf16_t* __restrict__ xproj) {     // [8192][2048] bf16, row = t*128+b
    int lane = threadIdx.x & 63, w = threadIdx.x >> 6;
    int r0 = blockIdx.x * 32 + (w & 1) * 16;       // row tile
    int g0 = blockIdx.y * 128 + (w >> 1) * 64;     // col tile
    f32x4 acc[4] = {};
    #pragma unroll
    for (int k = 0; k < EMB; k += 32) {
        bf16x8 a = frag16(A, r0, EMB, k, lane);
        #pragma unroll
        for (int t = 0; t < 4; t++) {
            bf16x8 b = frag16(Wih, g0 + 16 * t, EMB, k, lane);
            acc[t] = MFMA16(a, b, acc[t], 0, 0, 0);
        }
    }
    #pragma unroll
    for (int t = 0; t < 4; t++) {
        int g = g0 + 16 * t + (lane & 15);
        float bs = biassum[g];
        #pragma unroll
        for (int r = 0; r < 4; r++) {
            int row = r0 + ((lane >> 4) << 2) + r;
            xproj[(size_t)row * GATES + g] = (bf16_t)(acc[t][r] + bs);
        }
    }
}

// ---------------- recurrence: 8 blocks x 16 batch rows, ALL intra-block ----------------
// Block = 1024 threads = 16 waves, 1 CU. Wave w owns j-strip [w*32, w*32+32) for ALL 4 gates
// (8 MFMA tiles), so the cell update is wave-local: no gate exchange, no grid sync.
// h lives in LDS in MFMA A-fragment order ([kt][lane][8 bf16] -> lane-linear ds_read_b128,
// conflict-free). c stays in registers. Whh streams from L2 (resident after step 0).
__global__ __launch_bounds__(1024, 1) void k_rnn(
    const bf16_t* __restrict__ xp,    // [8192][2048] bf16, row = t*128+b
    const bf16_t* __restrict__ whh,   // [2048][512] bf16
    bf16_t* __restrict__ hfin) {      // [128][512] final h
    __shared__ bf16_t hfrag[2][16 * 512];   // fragment layout, double-buffered (32KB)
    const int tid = threadIdx.x;
    const int lane = tid & 63, w = tid >> 6;
    const int jj = lane & 15, q = lane >> 4;
    const int group = blockIdx.x;           // batch rows group*16 .. group*16+15
    const int jw = w * 32;

    // h0 = 0
    for (int i = tid; i < 16 * 512; i += 1024) hfrag[0][i] = (bf16_t)0.f;
    __syncthreads();

    float c[2][4] = {};   // cell state: [s][rr] for row q*4+rr, col jw + s*16 + jj

    for (int t = 0; t < TSTEPS; ++t) {
        const bf16_t* hs = hfrag[t & 1];
        bf16_t*       hd = hfrag[(t + 1) & 1];

        // xproj values for this thread's 8 cells x 4 gates (independent of h; issue early)
        const bf16_t* xrow = xp + ((size_t)(t * BATCH + group * 16 + q * 4)) * GATES + jw + jj;
        bf16_t xv[4][2][4];
        #pragma unroll
        for (int gt = 0; gt < 4; ++gt)
            #pragma unroll
            for (int s = 0; s < 2; ++s)
                #pragma unroll
                for (int rr = 0; rr < 4; ++rr)
                    xv[gt][s][rr] = xrow[(size_t)rr * GATES + gt * HID + s * 16];

        // gates GEMM: 16 rows x 32 cols x 4 gates, K=512
        f32x4 acc[4][2] = {};
        #pragma unroll 2
        for (int kt = 0; kt < 16; ++kt) {
            bf16x8 a = *(const bf16x8*)(hs + kt * 512 + lane * 8);   // conflict-free
            #pragma unroll
            for (int gt = 0; gt < 4; ++gt)
                #pragma unroll
                for (int s = 0; s < 2; ++s)
                    acc[gt][s] = MFMA16(a, frag16(whh, gt * HID + jw + s * 16, HID, kt * 32, lane),
                                        acc[gt][s], 0, 0, 0);
        }

        // cell update (fully wave-local) + h write in fragment layout
        #pragma unroll
        for (int s = 0; s < 2; ++s) {
            #pragma unroll
            for (int rr = 0; rr < 4; ++rr) {
                float iv = acc[0][s][rr] + (float)xv[0][s][rr];
                float fv = acc[1][s][rr] + (float)xv[1][s][rr];
                float gv = acc[2][s][rr] + (float)xv[2][s][rr];
                float ov = acc[3][s][rr] + (float)xv[3][s][rr];
                float cn = sigm(fv) * c[s][rr] + sigm(iv) * tanh_f(gv);
                c[s][rr] = cn;
                bf16_t hb = (bf16_t)(sigm(ov) * tanh_f(cn));
                int j = jw + s * 16 + jj;          // hidden col
                int row = q * 4 + rr;              // local batch row
                int kk = j & 31;
                // fragment position: kt = j>>5 (= w), lane_c = ((kk>>3)<<4)|row, elem = kk&7
                hd[(j >> 5) * 512 + ((((kk >> 3) << 4) | row) << 3) + (kk & 7)] = hb;
                if (t == TSTEPS - 1)
                    hfin[(size_t)(group * 16 + row) * HID + j] = hb;
            }
        }
        __syncthreads();
    }
}

// ---------------- output GEMM: h[128,512] x Wout^T + b_out -> out f32 [128][2048] ------------
__global__ __launch_bounds__(256) void k_out(
    const bf16_t* __restrict__ h,      // hfin
    const bf16_t* __restrict__ Wout,   // [2048][512] bf16
    const float* __restrict__ bout,
    float* __restrict__ out) {
    int lane = threadIdx.x & 63, w = threadIdx.x >> 6;
    int r0 = blockIdx.x * 32 + (w & 1) * 16;
    int g0 = blockIdx.y * 128 + (w >> 1) * 64;
    f32x4 acc[4] = {};
    #pragma unroll 4
    for (int k = 0; k < HID; k += 32) {
        bf16x8 a = frag16(h, r0, HID, k, lane);
        #pragma unroll
        for (int t = 0; t < 4; t++) {
            bf16x8 b = frag16(Wout, g0 + 16 * t, HID, k, lane);
            acc[t] = MFMA16(a, b, acc[t], 0, 0, 0);
        }
    }
    #pragma unroll
    for (int t = 0; t < 4; t++) {
        int g = g0 + 16 * t + (lane & 15);
        float bs = bout[g];
        #pragma unroll
        for (int r = 0; r < 4; r++) {
            int row = r0 + ((lane >> 4) << 2) + r;
            out[(size_t)row * NFEAT + g] = acc[t][r] + bs;
        }
    }
}

extern "C" void kernel_launch(void* const* d_in, const int* in_sizes, int n_in,
                              void* d_out, int out_size, void* d_ws, size_t ws_size,
                              hipStream_t stream) {
    const int*   m       = (const int*)d_in[0];
    // d_in[1] = images (unused by reference)
    const float* emb_tab = (const float*)d_in[2];
    const float* W_ih    = (const float*)d_in[3];
    const float* W_hh    = (const float*)d_in[4];
    const float* b_ih    = (const float*)d_in[5];
    const float* b_hh    = (const float*)d_in[6];
    const float* W_out   = (const float*)d_in[7];
    const float* b_out   = (const float*)d_in[8];

    char* ws = (char*)d_ws;
    bf16_t* xpb     = (bf16_t*)(ws + 0);          // 8192*2048*2 = 33554432
    bf16_t* emb_b   = (bf16_t*)(ws + 33554432);   // 4194304
    bf16_t* wih_b   = (bf16_t*)(ws + 37748736);   // 1048576
    bf16_t* whh_b   = (bf16_t*)(ws + 38797312);   // 2097152
    bf16_t* wout_b  = (bf16_t*)(ws + 40894464);   // 2097152
    bf16_t* hfin    = (bf16_t*)(ws + 42991616);   // 131072
    float*  biassum = (float*) (ws + 43122688);   // 8192

    k_prep<<<dim3(2048), dim3(256), 0, stream>>>(W_ih, W_hh, W_out, b_ih, b_hh, m, emb_tab,
                                                 wih_b, whh_b, wout_b, biassum, emb_b);

    k_xproj<<<dim3(256, 16), dim3(256), 0, stream>>>(emb_b, wih_b, biassum, xpb);

    k_rnn<<<dim3(8), dim3(1024), 0, stream>>>(xpb, whh_b, hfin);

    k_out<<<dim3(4, 16), dim3(256), 0, stream>>>(hfin, wout_b, b_out, (float*)d_out);
}

// Round 4
// 316.492 us; speedup vs baseline: 12.6531x; 12.6531x over previous
//
#include <hip/hip_runtime.h>
#include <hip/hip_bf16.h>

// Problem constants
#define BATCH 128
#define TSTEPS 64
#define EMB 256
#define HID 512
#define GATES 2048   // 4*HID
#define NFEAT 2048

typedef __bf16 bf16_t;
typedef __attribute__((ext_vector_type(8))) __bf16 bf16x8;
typedef __attribute__((ext_vector_type(4))) float f32x4;

#define MFMA16 __builtin_amdgcn_mfma_f32_16x16x32_bf16

// A/B fragment from row-major global: lane l -> row = row0 + (l&15), k = k0 + (l>>4)*8.
__device__ __forceinline__ bf16x8 frag16(const bf16_t* __restrict__ base, int row0, int stride,
                                         int k0, int lane) {
    return *(const bf16x8*)(base + (size_t)(row0 + (lane & 15)) * stride + k0 + ((lane >> 4) << 3));
}

__device__ __forceinline__ float sigm(float x) { return 1.f / (1.f + __expf(-x)); }
__device__ __forceinline__ float tanh_f(float x) { return 1.f - 2.f / (__expf(2.f * x) + 1.f); }

// System-scope (LLC-coherent, sc0sc1) 4B ops — bypass L1/L2, NO cache-invalidate fences.
__device__ __forceinline__ unsigned ld_sys(const unsigned* p) {
    return __hip_atomic_load(p, __ATOMIC_RELAXED, __HIP_MEMORY_SCOPE_SYSTEM);
}
__device__ __forceinline__ void st_sys(unsigned* p, unsigned v) {
    __hip_atomic_store(p, v, __ATOMIC_RELAXED, __HIP_MEMORY_SCOPE_SYSTEM);
}

__device__ __forceinline__ float bflo(unsigned w) {
    return __builtin_bit_cast(float, (w & 0xffffu) << 16);
}
__device__ __forceinline__ float bfhi(unsigned w) {
    return __builtin_bit_cast(float, w & 0xffff0000u);
}
__device__ __forceinline__ unsigned f2bf(float x) {
    return (unsigned)__builtin_bit_cast(unsigned short, (bf16_t)x);
}

// ---------------- prep: weights->bf16, gather emb (t-major), bias sum, zero h0+cnt ----------
__global__ __launch_bounds__(256) void k_prep(
    const float* __restrict__ Wih, const float* __restrict__ Whh, const float* __restrict__ Wout,
    const float* __restrict__ bih, const float* __restrict__ bhh,
    const int* __restrict__ m, const float* __restrict__ emb_tab,
    bf16_t* __restrict__ wih_b, bf16_t* __restrict__ whh_b, bf16_t* __restrict__ wout_b,
    float* __restrict__ biassum, bf16_t* __restrict__ emb_b,
    bf16_t* __restrict__ h0, unsigned* __restrict__ cnt) {
    const int N1 = GATES * EMB;          // Wih
    const int N2 = GATES * HID;          // Whh
    const int N3 = NFEAT * HID;          // Wout
    const int N4 = GATES;                // bias sum
    const int N5 = BATCH * TSTEPS * EMB; // gather (t-major rows)
    const int N6 = BATCH * HID;          // hbuf[0] zero
    const int N7 = 256;                  // cnt dwords
    const long total = (long)N1 + N2 + N3 + N4 + N5 + N6 + N7;
    for (long i = (long)blockIdx.x * blockDim.x + threadIdx.x; i < total;
         i += (long)gridDim.x * blockDim.x) {
        long x = i;
        if (x < N1) { wih_b[x] = (bf16_t)Wih[x]; continue; } x -= N1;
        if (x < N2) { whh_b[x] = (bf16_t)Whh[x]; continue; } x -= N2;
        if (x < N3) { wout_b[x] = (bf16_t)Wout[x]; continue; } x -= N3;
        if (x < N4) { biassum[x] = bih[x] + bhh[x]; continue; } x -= N4;
        if (x < N5) {
            int e = (int)(x & (EMB - 1));
            int rt = (int)(x >> 8);            // rt = t*128 + b  (t-major)
            int t = rt >> 7, b = rt & 127;
            int tok = m[b * TSTEPS + t];
            emb_b[x] = (bf16_t)emb_tab[(size_t)tok * EMB + e];
            continue;
        } x -= N5;
        if (x < N6) { h0[x] = (bf16_t)0.f; continue; } x -= N6;
        cnt[x] = 0u;
    }
}

// ---------------- x_proj GEMM: emb[8192,256] x Wih^T -> xproj bf16 [t*128+b][2048] (+bias) ----
__global__ __launch_bounds__(256) void k_xproj(
    const bf16_t* __restrict__ A, const bf16_t* __restrict__ Wih,
    const float* __restrict__ biassum, bf16_t* __restrict__ xproj) {
    int lane = threadIdx.x & 63, w = threadIdx.x >> 6;
    int r0 = blockIdx.x * 32 + (w & 1) * 16;
    int g0 = blockIdx.y * 128 + (w >> 1) * 64;
    f32x4 acc[4] = {};
    #pragma unroll
    for (int k = 0; k < EMB; k += 32) {
        bf16x8 a = frag16(A, r0, EMB, k, lane);
        #pragma unroll
        for (int t = 0; t < 4; t++) {
            bf16x8 b = frag16(Wih, g0 + 16 * t, EMB, k, lane);
            acc[t] = MFMA16(a, b, acc[t], 0, 0, 0);
        }
    }
    #pragma unroll
    for (int t = 0; t < 4; t++) {
        int g = g0 + 16 * t + (lane & 15);
        float bs = biassum[g];
        #pragma unroll
        for (int r = 0; r < 4; r++) {
            int row = r0 + ((lane >> 4) << 2) + r;
            xproj[(size_t)row * GATES + g] = (bf16_t)(acc[t][r] + bs);
        }
    }
}

// ---------------- recurrence: 64 blocks = 8 batch-groups x 8 hidden-strips ----------------
// Block (group, s): batch rows group*16..+16, gate-cols strip s*64..+64 (x 4 gates).
// 512 threads = 8 waves; wave w: gate g=w>>1, col-half hh=w&1 (32 cols = 2 MFMA tiles).
// Whh slice in REGISTERS (32 B-frags/wave, loop-invariant). h exchanged via LLC with
// sc0sc1 relaxed system atomics (no L2 invalidation); per-group aggregate counter barrier.
// hbuf layout: [parity][group][s][16 r][64 c] bf16.
__global__ __launch_bounds__(512, 2) void k_rnn(
    const bf16_t* __restrict__ xp,    // [8192][2048] bf16
    const bf16_t* __restrict__ whh,   // [2048][512] bf16
    bf16_t* __restrict__ hbuf,        // [2][128][512] piece layout
    unsigned* __restrict__ cnt) {
    __shared__ bf16_t hstage[16 * 512];     // 16KB, swizzled MFMA-frag layout
    __shared__ float gex[4][16][66];        // gate exchange, padded
    const int tid = threadIdx.x;
    const int lane = tid & 63, w = tid >> 6;
    const int group = blockIdx.x >> 3;      // 0..7
    const int s     = blockIdx.x & 7;       // 0..7
    const int g = w >> 1, hh = w & 1;

    // --- preload Whh slice into registers: 2 col-tiles x 16 k-tiles ---
    bf16x8 Bf0[16], Bf1[16];
    {
        const bf16_t* wb = whh + (size_t)(g * HID + s * 64 + hh * 32) * HID;
        #pragma unroll
        for (int kt = 0; kt < 16; ++kt) {
            Bf0[kt] = frag16(wb, 0, HID, kt * 32, lane);
            Bf1[kt] = frag16(wb, 16, HID, kt * 32, lane);
        }
    }

    const int r_up = tid >> 5;              // 0..15 (batch row within group)
    const int c0 = (tid & 31) * 2;          // 0..62 (local col pair)
    float cst0 = 0.f, cst1 = 0.f;           // cell state (persistent in regs)
    unsigned* myflag = cnt + group * 32;

    for (int t = 0; t < TSTEPS; ++t) {
        if (t) {
            if (tid == 0) {
                unsigned tgt = (unsigned)(8 * t);
                while (ld_sys(myflag) < tgt) __builtin_amdgcn_s_sleep(2);
            }
            __syncthreads();
            asm volatile("" ::: "memory");
        }

        // xproj loads (independent of h; L2-cached regular loads)
        unsigned xw0, xw1, xw2, xw3;
        {
            const bf16_t* xrow = xp + ((size_t)t * BATCH + group * 16 + r_up) * GATES + s * 64 + c0;
            xw0 = *(const unsigned*)(xrow);
            xw1 = *(const unsigned*)(xrow + HID);
            xw2 = *(const unsigned*)(xrow + 2 * HID);
            xw3 = *(const unsigned*)(xrow + 3 * HID);
        }

        // --- stage h_t (group's 16KB) from LLC into LDS frag layout (swizzled) ---
        {
            const unsigned* gsrc = (const unsigned*)hbuf + (size_t)(t & 1) * (BATCH * HID / 2)
                                 + (size_t)group * 4096;
            unsigned d[2][4];
            #pragma unroll
            for (int k2 = 0; k2 < 2; ++k2) {
                int n = tid + k2 * 512;
                #pragma unroll
                for (int j = 0; j < 4; ++j) d[k2][j] = ld_sys(gsrc + n * 4 + j);
            }
            #pragma unroll
            for (int k2 = 0; k2 < 2; ++k2) {
                int n = tid + k2 * 512;                  // 16B chunk id
                int sp = n >> 7, r = (n >> 3) & 15, c16 = n & 7;
                int kt = sp * 2 + (c16 >> 2), ch = c16 & 3;
                int u = (kt << 6) + (((r << 2) ^ (r & 7)) ^ ch);
                *(uint4*)((char*)hstage + (size_t)u * 16) =
                    make_uint4(d[k2][0], d[k2][1], d[k2][2], d[k2][3]);
            }
        }
        __syncthreads();

        // --- gates GEMM: 16 rows x 32 cols, K=512, B in registers ---
        f32x4 a0 = {}, a1 = {};
        {
            const int ubase = (((((lane & 15) << 2) ^ (lane & 7)) ^ (lane >> 4)) << 4);
            #pragma unroll
            for (int kt = 0; kt < 16; ++kt) {
                bf16x8 a = *(const bf16x8*)((const char*)hstage + kt * 1024 + ubase);
                a0 = MFMA16(a, Bf0[kt], a0, 0, 0, 0);
                a1 = MFMA16(a, Bf1[kt], a1, 0, 0, 0);
            }
        }

        // --- gate exchange via LDS ---
        {
            const int jj = lane & 15, q = lane >> 4;
            #pragma unroll
            for (int rr = 0; rr < 4; ++rr) {
                gex[g][q * 4 + rr][hh * 32 + jj]      = a0[rr];
                gex[g][q * 4 + rr][hh * 32 + 16 + jj] = a1[rr];
            }
        }
        __syncthreads();

        // --- cell update (2 cells/thread) + h piece store to LLC ---
        {
            float iv0 = gex[0][r_up][c0]     + bflo(xw0);
            float fv0 = gex[1][r_up][c0]     + bflo(xw1);
            float gv0 = gex[2][r_up][c0]     + bflo(xw2);
            float ov0 = gex[3][r_up][c0]     + bflo(xw3);
            float iv1 = gex[0][r_up][c0 + 1] + bfhi(xw0);
            float fv1 = gex[1][r_up][c0 + 1] + bfhi(xw1);
            float gv1 = gex[2][r_up][c0 + 1] + bfhi(xw2);
            float ov1 = gex[3][r_up][c0 + 1] + bfhi(xw3);
            cst0 = sigm(fv0) * cst0 + sigm(iv0) * tanh_f(gv0);
            cst1 = sigm(fv1) * cst1 + sigm(iv1) * tanh_f(gv1);
            float h0v = sigm(ov0) * tanh_f(cst0);
            float h1v = sigm(ov1) * tanh_f(cst1);
            unsigned pack = f2bf(h0v) | (f2bf(h1v) << 16);
            unsigned* hd = (unsigned*)hbuf + (size_t)((t + 1) & 1) * (BATCH * HID / 2)
                         + (size_t)group * 4096 + s * 512 + tid;
            st_sys(hd, pack);
        }
        __syncthreads();   // drains the sc0sc1 stores (pre-barrier vmcnt(0))
        if (tid == 0)
            __hip_atomic_fetch_add(myflag, 1u, __ATOMIC_RELAXED, __HIP_MEMORY_SCOPE_SYSTEM);
    }
}

// A-frag from hbuf piece layout [group][s][16 r][64 c]
__device__ __forceinline__ bf16x8 frag_piece(const bf16_t* hb, int group, int kt, int lane) {
    const char* p = (const char*)hb + (size_t)group * 16384 + (kt >> 1) * 2048
                  + (lane & 15) * 128 + (kt & 1) * 64 + ((lane >> 4) << 4);
    return *(const bf16x8*)p;
}

// ---------------- output GEMM: h[128,512] x Wout^T + b_out -> out f32 [128][2048] ------------
__global__ __launch_bounds__(256) void k_out(
    const bf16_t* __restrict__ h,      // hbuf[0] piece layout
    const bf16_t* __restrict__ Wout,
    const float* __restrict__ bout,
    float* __restrict__ out) {
    int lane = threadIdx.x & 63, w = threadIdx.x >> 6;
    int r0 = blockIdx.x * 32 + (w & 1) * 16;
    int g0 = blockIdx.y * 128 + (w >> 1) * 64;
    int group = r0 >> 4;
    f32x4 acc[4] = {};
    #pragma unroll 4
    for (int kt = 0; kt < 16; ++kt) {
        bf16x8 a = frag_piece(h, group, kt, lane);
        #pragma unroll
        for (int t = 0; t < 4; t++) {
            bf16x8 b = frag16(Wout, g0 + 16 * t, HID, kt * 32, lane);
            acc[t] = MFMA16(a, b, acc[t], 0, 0, 0);
        }
    }
    #pragma unroll
    for (int t = 0; t < 4; t++) {
        int g = g0 + 16 * t + (lane & 15);
        float bs = bout[g];
        #pragma unroll
        for (int r = 0; r < 4; r++) {
            int row = r0 + ((lane >> 4) << 2) + r;
            out[(size_t)row * NFEAT + g] = acc[t][r] + bs;
        }
    }
}

extern "C" void kernel_launch(void* const* d_in, const int* in_sizes, int n_in,
                              void* d_out, int out_size, void* d_ws, size_t ws_size,
                              hipStream_t stream) {
    const int*   m       = (const int*)d_in[0];
    // d_in[1] = images (unused by reference)
    const float* emb_tab = (const float*)d_in[2];
    const float* W_ih    = (const float*)d_in[3];
    const float* W_hh    = (const float*)d_in[4];
    const float* b_ih    = (const float*)d_in[5];
    const float* b_hh    = (const float*)d_in[6];
    const float* W_out   = (const float*)d_in[7];
    const float* b_out   = (const float*)d_in[8];

    char* ws = (char*)d_ws;
    bf16_t*   xpb     = (bf16_t*)  (ws + 0);          // 33554432
    bf16_t*   emb_b   = (bf16_t*)  (ws + 33554432);   // 4194304
    bf16_t*   wih_b   = (bf16_t*)  (ws + 37748736);   // 1048576
    bf16_t*   whh_b   = (bf16_t*)  (ws + 38797312);   // 2097152
    bf16_t*   wout_b  = (bf16_t*)  (ws + 40894464);   // 2097152
    bf16_t*   hbuf    = (bf16_t*)  (ws + 42991616);   // 2*131072 = 262144
    float*    biassum = (float*)   (ws + 43253760);   // 8192
    unsigned* cnt     = (unsigned*)(ws + 43261952);   // 1024

    k_prep<<<dim3(2048), dim3(256), 0, stream>>>(W_ih, W_hh, W_out, b_ih, b_hh, m, emb_tab,
                                                 wih_b, whh_b, wout_b, biassum, emb_b,
                                                 hbuf /*hbuf[0]=h0*/, cnt);

    k_xproj<<<dim3(256, 16), dim3(256), 0, stream>>>(emb_b, wih_b, biassum, xpb);

    k_rnn<<<dim3(64), dim3(512), 0, stream>>>(xpb, whh_b, hbuf, cnt);

    // t=63 writes parity (63+1)&1 = 0 -> final h in hbuf[0]
    k_out<<<dim3(4, 16), dim3(256), 0, stream>>>(hbuf, wout_b, b_out, (float*)d_out);
}

// Round 5
// 233.635 us; speedup vs baseline: 17.1404x; 1.3546x over previous
//
#include <hip/hip_runtime.h>
#include <hip/hip_bf16.h>

// Problem constants
#define BATCH 128
#define TSTEPS 64
#define EMB 256
#define HID 512
#define GATES 2048   // 4*HID
#define NFEAT 2048

typedef __bf16 bf16_t;
typedef __attribute__((ext_vector_type(8))) __bf16 bf16x8;
typedef __attribute__((ext_vector_type(4))) float f32x4;

#define MFMA16 __builtin_amdgcn_mfma_f32_16x16x32_bf16

// A/B fragment from row-major global: lane l -> row = row0 + (l&15), k = k0 + (l>>4)*8.
__device__ __forceinline__ bf16x8 frag16(const bf16_t* __restrict__ base, int row0, int stride,
                                         int k0, int lane) {
    return *(const bf16x8*)(base + (size_t)(row0 + (lane & 15)) * stride + k0 + ((lane >> 4) << 3));
}

__device__ __forceinline__ float sigm(float x) { return 1.f / (1.f + __expf(-x)); }
__device__ __forceinline__ float tanh_f(float x) { return 1.f - 2.f / (__expf(2.f * x) + 1.f); }

// System-scope (LLC-coherent, sc0sc1) ops — bypass L1/L2, no cache-invalidate fences.
__device__ __forceinline__ unsigned ld_sys(const unsigned* p) {
    return __hip_atomic_load(p, __ATOMIC_RELAXED, __HIP_MEMORY_SCOPE_SYSTEM);
}
__device__ __forceinline__ void st_sys(unsigned* p, unsigned v) {
    __hip_atomic_store(p, v, __ATOMIC_RELAXED, __HIP_MEMORY_SCOPE_SYSTEM);
}
// Two 16B LLC-bypass loads in flight, one wait.
__device__ __forceinline__ void ld2_sys_v4(const void* p0, const void* p1, uint4& a, uint4& b) {
    asm volatile("global_load_dwordx4 %0, %2, off sc0 sc1\n\t"
                 "global_load_dwordx4 %1, %3, off sc0 sc1\n\t"
                 "s_waitcnt vmcnt(0)"
                 : "=&v"(a), "=&v"(b)
                 : "v"(p0), "v"(p1)
                 : "memory");
}

__device__ __forceinline__ float bflo(unsigned w) {
    return __builtin_bit_cast(float, (w & 0xffffu) << 16);
}
__device__ __forceinline__ float bfhi(unsigned w) {
    return __builtin_bit_cast(float, w & 0xffff0000u);
}
__device__ __forceinline__ unsigned f2bf(float x) {
    return (unsigned)__builtin_bit_cast(unsigned short, (bf16_t)x);
}

// ---------------- prep: weights->bf16, gather emb (t-major), bias sum, zero h0+cnt ----------
__global__ __launch_bounds__(256) void k_prep(
    const float* __restrict__ Wih, const float* __restrict__ Whh, const float* __restrict__ Wout,
    const float* __restrict__ bih, const float* __restrict__ bhh,
    const int* __restrict__ m, const float* __restrict__ emb_tab,
    bf16_t* __restrict__ wih_b, bf16_t* __restrict__ whh_b, bf16_t* __restrict__ wout_b,
    float* __restrict__ biassum, bf16_t* __restrict__ emb_b,
    bf16_t* __restrict__ h0, unsigned* __restrict__ cnt) {
    const int N1 = GATES * EMB;
    const int N2 = GATES * HID;
    const int N3 = NFEAT * HID;
    const int N4 = GATES;
    const int N5 = BATCH * TSTEPS * EMB;
    const int N6 = BATCH * HID;          // hbuf parity 0 zero
    const int N7 = 256;                  // cnt dwords
    const long total = (long)N1 + N2 + N3 + N4 + N5 + N6 + N7;
    for (long i = (long)blockIdx.x * blockDim.x + threadIdx.x; i < total;
         i += (long)gridDim.x * blockDim.x) {
        long x = i;
        if (x < N1) { wih_b[x] = (bf16_t)Wih[x]; continue; } x -= N1;
        if (x < N2) { whh_b[x] = (bf16_t)Whh[x]; continue; } x -= N2;
        if (x < N3) { wout_b[x] = (bf16_t)Wout[x]; continue; } x -= N3;
        if (x < N4) { biassum[x] = bih[x] + bhh[x]; continue; } x -= N4;
        if (x < N5) {
            int e = (int)(x & (EMB - 1));
            int rt = (int)(x >> 8);            // rt = t*128 + b  (t-major)
            int t = rt >> 7, b = rt & 127;
            int tok = m[b * TSTEPS + t];
            emb_b[x] = (bf16_t)emb_tab[(size_t)tok * EMB + e];
            continue;
        } x -= N5;
        if (x < N6) { h0[x] = (bf16_t)0.f; continue; } x -= N6;
        cnt[x] = 0u;
    }
}

// ---------------- x_proj GEMM: emb[8192,256] x Wih^T -> xproj bf16 [t*128+b][2048] (+bias) ----
// 128x128 block tile, 4 waves (2x2), each wave 64x64 = 4x4 frags -> 4x B/A reuse.
__global__ __launch_bounds__(256) void k_xproj(
    const bf16_t* __restrict__ A, const bf16_t* __restrict__ Wih,
    const float* __restrict__ biassum, bf16_t* __restrict__ xproj) {
    int lane = threadIdx.x & 63, w = threadIdx.x >> 6;
    int r0 = blockIdx.x * 128 + (w >> 1) * 64;
    int g0 = blockIdx.y * 128 + (w & 1) * 64;
    f32x4 acc[4][4] = {};
    #pragma unroll
    for (int k = 0; k < EMB; k += 32) {
        bf16x8 af[4], bf[4];
        #pragma unroll
        for (int i = 0; i < 4; i++) af[i] = frag16(A, r0 + 16 * i, EMB, k, lane);
        #pragma unroll
        for (int j = 0; j < 4; j++) bf[j] = frag16(Wih, g0 + 16 * j, EMB, k, lane);
        #pragma unroll
        for (int i = 0; i < 4; i++)
            #pragma unroll
            for (int j = 0; j < 4; j++)
                acc[i][j] = MFMA16(af[i], bf[j], acc[i][j], 0, 0, 0);
    }
    #pragma unroll
    for (int j = 0; j < 4; j++) {
        int g = g0 + 16 * j + (lane & 15);
        float bs = biassum[g];
        #pragma unroll
        for (int i = 0; i < 4; i++)
            #pragma unroll
            for (int r = 0; r < 4; r++) {
                int row = r0 + 16 * i + ((lane >> 4) << 2) + r;
                xproj[(size_t)row * GATES + g] = (bf16_t)(acc[i][j][r] + bs);
            }
    }
}

// ---------------- recurrence: 64 blocks = 8 batch-groups x 8 hidden-strips ----------------
// Block (group, s): batch rows group*16..+16, j-cols [s*64, s*64+64) for all 4 gates.
// 512 threads = 8 waves; wave w: gate g=w>>1, col-half hh=w&1 (32 cols = 2 MFMA tiles).
// Whh slice pinned in REGISTERS (asm keep-alive). h exchanged via LLC in MFMA-FRAGMENT
// layout: [parity][group][16 kt][64 lane][8 bf16] — producers store straight into frag
// positions, consumers do a pure 16B copy into LDS (no remap, no swizzle).
__global__ __launch_bounds__(512, 1) void k_rnn(
    const bf16_t* __restrict__ xp,    // [8192][2048] bf16
    const bf16_t* __restrict__ whh,   // [2048][512] bf16
    bf16_t* __restrict__ hbuf,        // [2][8 groups][16KB frag pieces]
    unsigned* __restrict__ cnt) {
    __shared__ __align__(16) char hstage[16384];   // [16 kt][64 lane][16B]
    __shared__ float gex[4][16][66];               // gate exchange
    const int tid = threadIdx.x;
    const int lane = tid & 63, w = tid >> 6;
    const int group = blockIdx.x >> 3;      // 0..7
    const int s     = blockIdx.x & 7;       // 0..7
    const int g = w >> 1, hh = w & 1;

    // --- preload Whh slice into registers and PIN it there ---
    bf16x8 Bf0[16], Bf1[16];
    {
        const bf16_t* wb = whh + (size_t)(g * HID + s * 64 + hh * 32) * HID;
        #pragma unroll
        for (int kt = 0; kt < 16; ++kt) {
            Bf0[kt] = frag16(wb, 0, HID, kt * 32, lane);
            Bf1[kt] = frag16(wb, 16, HID, kt * 32, lane);
        }
        #pragma unroll
        for (int kt = 0; kt < 16; ++kt)
            asm volatile("" : "+v"(Bf0[kt]), "+v"(Bf1[kt]));
    }

    const int r_up = tid >> 5;              // 0..15 (batch row within group)
    const int c0 = (tid & 31) * 2;          // 0..62 (local col pair)
    float cst0 = 0.f, cst1 = 0.f;           // cell state (persistent in regs)
    unsigned* myflag = cnt + group * 32;

    // precomputed h-store position (fragment layout)
    unsigned* hstore_base;
    {
        int j = s * 64 + c0;                           // group-local hidden col
        int kt = j >> 5;
        int lane_p = (((j & 31) >> 3) << 4) | r_up;
        hstore_base = (unsigned*)hbuf + (size_t)group * 4096 + kt * 256 + lane_p * 4 + ((j & 7) >> 1);
    }

    for (int t = 0; t < TSTEPS; ++t) {
        // xproj prefetch BEFORE the flag wait (independent of h; HBM latency hides under wait)
        unsigned xw0, xw1, xw2, xw3;
        {
            const bf16_t* xrow = xp + ((size_t)t * BATCH + group * 16 + r_up) * GATES + s * 64 + c0;
            xw0 = *(const unsigned*)(xrow);
            xw1 = *(const unsigned*)(xrow + HID);
            xw2 = *(const unsigned*)(xrow + 2 * HID);
            xw3 = *(const unsigned*)(xrow + 3 * HID);
        }

        if (t) {
            if (tid == 0) {
                unsigned tgt = (unsigned)(8 * t);
                while (ld_sys(myflag) < tgt) __builtin_amdgcn_s_sleep(1);
            }
            __syncthreads();
            asm volatile("" ::: "memory");
        }

        // --- stage h_t: pure 16B copy LLC -> LDS (already in fragment layout) ---
        {
            const char* gsrc = (const char*)hbuf + (size_t)(t & 1) * 131072
                             + (size_t)group * 16384;
            uint4 va, vb;
            ld2_sys_v4(gsrc + (size_t)tid * 16, gsrc + (size_t)(tid + 512) * 16, va, vb);
            *(uint4*)(hstage + (size_t)tid * 16) = va;
            *(uint4*)(hstage + (size_t)(tid + 512) * 16) = vb;
        }
        __syncthreads();

        // --- gates GEMM: 16 rows x 32 cols, K=512, B pinned in registers ---
        f32x4 a0 = {}, a1 = {};
        {
            const bf16_t* hs = (const bf16_t*)hstage;
            #pragma unroll
            for (int kt = 0; kt < 16; ++kt) {
                bf16x8 a = *(const bf16x8*)(hs + kt * 512 + lane * 8);   // lane-linear
                a0 = MFMA16(a, Bf0[kt], a0, 0, 0, 0);
                a1 = MFMA16(a, Bf1[kt], a1, 0, 0, 0);
            }
        }

        // --- gate exchange via LDS ---
        {
            const int jj = lane & 15, q = lane >> 4;
            #pragma unroll
            for (int rr = 0; rr < 4; ++rr) {
                gex[g][q * 4 + rr][hh * 32 + jj]      = a0[rr];
                gex[g][q * 4 + rr][hh * 32 + 16 + jj] = a1[rr];
            }
        }
        __syncthreads();

        // --- cell update (2 cells/thread) + h frag-store to LLC ---
        {
            float2 gi = *(const float2*)&gex[0][r_up][c0];
            float2 gf = *(const float2*)&gex[1][r_up][c0];
            float2 gg = *(const float2*)&gex[2][r_up][c0];
            float2 go = *(const float2*)&gex[3][r_up][c0];
            float iv0 = gi.x + bflo(xw0), iv1 = gi.y + bfhi(xw0);
            float fv0 = gf.x + bflo(xw1), fv1 = gf.y + bfhi(xw1);
            float gv0 = gg.x + bflo(xw2), gv1 = gg.y + bfhi(xw2);
            float ov0 = go.x + bflo(xw3), ov1 = go.y + bfhi(xw3);
            cst0 = sigm(fv0) * cst0 + sigm(iv0) * tanh_f(gv0);
            cst1 = sigm(fv1) * cst1 + sigm(iv1) * tanh_f(gv1);
            float h0v = sigm(ov0) * tanh_f(cst0);
            float h1v = sigm(ov1) * tanh_f(cst1);
            unsigned pack = f2bf(h0v) | (f2bf(h1v) << 16);
            st_sys(hstore_base + (size_t)(((t + 1) & 1)) * 32768, pack);
        }
        __syncthreads();   // per-wave vmcnt(0) drain before barrier -> stores complete
        if (tid == 0 && t < TSTEPS - 1)
            __hip_atomic_fetch_add(myflag, 1u, __ATOMIC_RELAXED, __HIP_MEMORY_SCOPE_SYSTEM);
    }
}

// A-frag from hbuf fragment-piece layout [group][16 kt][64 lane][8]
__device__ __forceinline__ bf16x8 frag_piece(const bf16_t* hb, int group, int kt, int lane) {
    return *(const bf16x8*)(hb + (size_t)group * 8192 + kt * 512 + lane * 8);
}

// ---------------- output GEMM: h[128,512] x Wout^T + b_out -> out f32 [128][2048] ------------
__global__ __launch_bounds__(256) void k_out(
    const bf16_t* __restrict__ h,      // hbuf parity 0, fragment-piece layout
    const bf16_t* __restrict__ Wout,
    const float* __restrict__ bout,
    float* __restrict__ out) {
    int lane = threadIdx.x & 63, w = threadIdx.x >> 6;
    int r0 = blockIdx.x * 32 + (w & 1) * 16;
    int g0 = blockIdx.y * 128 + (w >> 1) * 64;
    int group = r0 >> 4;
    f32x4 acc[4] = {};
    #pragma unroll 4
    for (int kt = 0; kt < 16; ++kt) {
        bf16x8 a = frag_piece(h, group, kt, lane);
        #pragma unroll
        for (int t = 0; t < 4; t++) {
            bf16x8 b = frag16(Wout, g0 + 16 * t, HID, kt * 32, lane);
            acc[t] = MFMA16(a, b, acc[t], 0, 0, 0);
        }
    }
    #pragma unroll
    for (int t = 0; t < 4; t++) {
        int g = g0 + 16 * t + (lane & 15);
        float bs = bout[g];
        #pragma unroll
        for (int r = 0; r < 4; r++) {
            int row = r0 + ((lane >> 4) << 2) + r;
            out[(size_t)row * NFEAT + g] = acc[t][r] + bs;
        }
    }
}

extern "C" void kernel_launch(void* const* d_in, const int* in_sizes, int n_in,
                              void* d_out, int out_size, void* d_ws, size_t ws_size,
                              hipStream_t stream) {
    const int*   m       = (const int*)d_in[0];
    // d_in[1] = images (unused by reference)
    const float* emb_tab = (const float*)d_in[2];
    const float* W_ih    = (const float*)d_in[3];
    const float* W_hh    = (const float*)d_in[4];
    const float* b_ih    = (const float*)d_in[5];
    const float* b_hh    = (const float*)d_in[6];
    const float* W_out   = (const float*)d_in[7];
    const float* b_out   = (const float*)d_in[8];

    char* ws = (char*)d_ws;
    bf16_t*   xpb     = (bf16_t*)  (ws + 0);          // 33554432
    bf16_t*   emb_b   = (bf16_t*)  (ws + 33554432);   // 4194304
    bf16_t*   wih_b   = (bf16_t*)  (ws + 37748736);   // 1048576
    bf16_t*   whh_b   = (bf16_t*)  (ws + 38797312);   // 2097152
    bf16_t*   wout_b  = (bf16_t*)  (ws + 40894464);   // 2097152
    bf16_t*   hbuf    = (bf16_t*)  (ws + 42991616);   // 2*131072 = 262144
    float*    biassum = (float*)   (ws + 43253760);   // 8192
    unsigned* cnt     = (unsigned*)(ws + 43261952);   // 1024

    k_prep<<<dim3(2048), dim3(256), 0, stream>>>(W_ih, W_hh, W_out, b_ih, b_hh, m, emb_tab,
                                                 wih_b, whh_b, wout_b, biassum, emb_b,
                                                 hbuf /*parity 0 = h0*/, cnt);

    k_xproj<<<dim3(64, 16), dim3(256), 0, stream>>>(emb_b, wih_b, biassum, xpb);

    k_rnn<<<dim3(64), dim3(512), 0, stream>>>(xpb, whh_b, hbuf, cnt);

    // t=63 writes parity (63+1)&1 = 0 -> final h in hbuf parity 0
    k_out<<<dim3(4, 16), dim3(256), 0, stream>>>(hbuf, wout_b, b_out, (float*)d_out);
}